// Round 2
// baseline (123.857 us; speedup 1.0000x reference)
//
#include <hip/hip_runtime.h>
#include <hip/hip_bf16.h>
#include <stdint.h>

// Problem constants
#define LL   4096
#define CCH  64
#define DOUT 512
#define MM   8192            // B*NP patch-rows
#define TT   0.001f          // 1/FS

using bf16 = __hip_bfloat16;
typedef __attribute__((ext_vector_type(8))) short bf16x8;
typedef __attribute__((ext_vector_type(4))) float f32x4;

__device__ __forceinline__ uint2 pack4_bf16(float a, float b, float c, float d) {
    union { bf16 h[4]; uint2 u; } p;
    p.h[0] = __float2bfloat16(a);
    p.h[1] = __float2bfloat16(b);
    p.h[2] = __float2bfloat16(c);
    p.h[3] = __float2bfloat16(d);
    return p.u;
}

// ---------------------------------------------------------------------------
// prep: repack weights PLAIN (no swizzle) into k-chunked layout so a wave's
// B-fragment global load is one contiguous 1 KB block:
//   w1g[ic][col][kk]  (ic=0..31, kk=0..31): = w1[col][l*32+j], k=ic*32+kk,
//                      l=k>>4, j=k&15   (x-part columns only)
//   w2g[ic2][col][kk] (ic2=0..15):        = w2[col][ic2*32+kk]
//   blocks [768,896): A1[o] = T*sum_l Wt[o][l]; C1[o] = b1[o]+T*sum_l l*Wt
//                     Wt[o][l] = sum_{j<16} w1[o][l*32+16+j]      (1 wave/o)
// ---------------------------------------------------------------------------
__global__ __launch_bounds__(256) void prep(
    const float* __restrict__ w1, const float* __restrict__ b1,
    const float* __restrict__ w2,
    bf16* __restrict__ w1g, bf16* __restrict__ w2g,
    float* __restrict__ A1, float* __restrict__ C1)
{
    const int blk = blockIdx.x;
    if (blk < 512) {
        int g   = blk * 256 + threadIdx.x;          // 0..131071, 4 elems each
        int kk0 = (g & 7) * 4;                      // 0,4,..,28
        int col = (g >> 3) & 511;
        int ic  = g >> 12;                          // 0..31
        int l   = ic * 2 + (kk0 >> 4);
        int j0  = kk0 & 15;
        float4 v = *(const float4*)(w1 + (size_t)col * 2048 + l * 32 + j0);
        *(uint2*)(w1g + ((size_t)(ic * 512 + col) * 32 + kk0)) =
            pack4_bf16(v.x, v.y, v.z, v.w);
    } else if (blk < 768) {
        int g   = (blk - 512) * 256 + threadIdx.x;  // 0..65535
        int kk0 = (g & 7) * 4;
        int col = (g >> 3) & 511;
        int ic2 = g >> 12;                          // 0..15
        float4 v = *(const float4*)(w2 + (size_t)col * 512 + ic2 * 32 + kk0);
        *(uint2*)(w2g + ((size_t)(ic2 * 512 + col) * 32 + kk0)) =
            pack4_bf16(v.x, v.y, v.z, v.w);
    } else {
        const int o = (blk - 768) * 4 + (threadIdx.x >> 6);
        const int l = threadIdx.x & 63;
        const float* wr = w1 + (size_t)o * 2048 + l * 32 + 16;
        float s0 = 0.f;
#pragma unroll
        for (int j = 0; j < 16; ++j) s0 += wr[j];
        float s1 = (float)l * s0;
#pragma unroll
        for (int off = 32; off > 0; off >>= 1) {
            s0 += __shfl_down(s0, off);
            s1 += __shfl_down(s1, off);
        }
        if (l == 0) {
            A1[o] = TT * s0;
            C1[o] = b1[o] + TT * s1;
        }
    }
}

// ---------------------------------------------------------------------------
// Megakernel v5: block = 32 patches x 512 outputs, both layers fused.
// v4 post-mortem: the 4-deep source-level ring was folded away by the
// compiler (VGPR stayed 76 -> loads were re-sunk next to uses) and dur
// REGRESSED 43.6->51.8us. Source-level SW pipelining does not bind hipcc.
// v5: fix latency-hiding via TLP instead. Grid=256 gives 1 block/CU, so
// 512-thread blocks meant only 2 waves/SIMD. Now 1024 threads (16 waves,
// 4 waves/SIMD), each wave owns 32 output cols (j-loop 2). Per-wave
// load:MFMA ratio, total L2 traffic (384 MB) and LDS (64.5 KB) unchanged.
// Loop structure reverted to the simple v3 1-deep form the compiler
// scheduled best; phase-B prologue loads + A1/C1/b2 hoisted under the
// epilogue/barriers (straight-line hoists survive scheduling).
// Only 3 __syncthreads in the whole kernel.
// ---------------------------------------------------------------------------
__global__ __launch_bounds__(1024, 4) void mega(
    const float* __restrict__ x, const int* __restrict__ sLg,
    const int* __restrict__ sCg, const bf16* __restrict__ w1g,
    const bf16* __restrict__ w2g, const float* __restrict__ A1,
    const float* __restrict__ C1, const float* __restrict__ b2,
    float* __restrict__ out)
{
    __shared__ __align__(16) bf16 Asm[32 * 1024];   // 64 KB; Hs overlays later
    __shared__ float slf[32];
    bf16* const Hs = Asm;                           // 32 x 512 after phase A

    const int t    = threadIdx.x;
    const int lane = t & 63;
    const int wave = t >> 6;            // 0..15, owns cols [wave*32, wave*32+32)
    const int fr   = lane & 15;
    const int fq   = lane >> 4;
    const int m0   = blockIdx.x * 32;
    const int b    = m0 >> 8;           // 32 rows lie within one batch

    // ---- Prologue: gather x into swizzled A-tile (one shot, 1024 threads)
    {
        const int gr  = t >> 5;         // patch row 0..31
        const int gs  = t & 31;         // 32 threads per patch row
        const int gsl = sLg[m0 + gr];
        const int gsc = sCg[m0 + gr];
        if (gs == 0) slf[gr] = (float)gsl;
        const int c4 = gs & 3;          // which float4 within a 16-ch row
        const int l0 = gs >> 2;         // 0..7 row phase
        const float* gx = x + ((size_t)b * LL + gsl + l0) * CCH
                            + gsc + c4 * 4;
        float4 xv[8];
#pragma unroll
        for (int p = 0; p < 8; ++p)
            xv[p] = *(const float4*)(gx + (size_t)p * 8 * CCH);
#pragma unroll
        for (int p = 0; p < 8; ++p) {
            const int l = p * 8 + l0;
            const int u = l * 2 + (c4 >> 1);            // k-unit = (l*16+j)>>3
            const int idx = gr * 1024 + ((u ^ (gr & 7)) * 8) + (c4 & 1) * 4;
            *(uint2*)(Asm + idx) = pack4_bf16(xv[p].x, xv[p].y, xv[p].z, xv[p].w);
        }
    }
    __syncthreads();                    // A-tile ready

    // ---- Phase A: 32 iters of k=32, B-frags direct from global (1-deep)
    const bf16* const w1base = w1g + (size_t)(wave * 32 + fr) * 32 + fq * 8;
    f32x4 acc[2][2] = {};
    {
        bf16x8 bnx[2];
#pragma unroll
        for (int j = 0; j < 2; ++j)
            bnx[j] = *(const bf16x8*)(w1base + j * 512);
#pragma unroll
        for (int it = 0; it < 32; ++it) {
            bf16x8 bcur[2];
#pragma unroll
            for (int j = 0; j < 2; ++j) bcur[j] = bnx[j];
            if (it < 31) {
                const bf16* p = w1base + (size_t)(it + 1) * 16384;
#pragma unroll
                for (int j = 0; j < 2; ++j)
                    bnx[j] = *(const bf16x8*)(p + j * 512);
            }
            bf16x8 af[2];
#pragma unroll
            for (int i = 0; i < 2; ++i) {
                const int row = i * 16 + fr;
                const int u   = it * 4 + fq;
                af[i] = *(const bf16x8*)&Asm[row * 1024 + ((u ^ (row & 7)) * 8)];
            }
#pragma unroll
            for (int i = 0; i < 2; ++i)
#pragma unroll
                for (int j = 0; j < 2; ++j)
                    acc[i][j] = __builtin_amdgcn_mfma_f32_16x16x32_bf16(
                        af[i], bcur[j], acc[i][j], 0, 0, 0);
        }
    }
    __syncthreads();                    // all A-frag reads done (Asm -> Hs)

    // ---- Issue phase-B prologue B-frags + A1/C1 now; they complete under
    //      the silu epilogue + barrier.
    const bf16* const w2base = w2g + (size_t)(wave * 32 + fr) * 32 + fq * 8;
    bf16x8 bnx2[2];
#pragma unroll
    for (int j = 0; j < 2; ++j)
        bnx2[j] = *(const bf16x8*)(w2base + j * 512);
    float avv[2], cvv[2];
#pragma unroll
    for (int j = 0; j < 2; ++j) {
        const int col = wave * 32 + j * 16 + fr;
        avv[j] = A1[col];
        cvv[j] = C1[col];
    }

    // ---- Phase A epilogue: silu(acc + sL*A1 + C1) -> Hs (swizzled)
    {
        float slr[2][4];
#pragma unroll
        for (int i = 0; i < 2; ++i)
#pragma unroll
            for (int rr = 0; rr < 4; ++rr)
                slr[i][rr] = slf[i * 16 + fq * 4 + rr];
#pragma unroll
        for (int j = 0; j < 2; ++j) {
            const int col = wave * 32 + j * 16 + fr;
            const float av = avv[j];
            const float cv = cvv[j];
            const int c8 = col >> 3, c7 = col & 7;
#pragma unroll
            for (int i = 0; i < 2; ++i)
#pragma unroll
                for (int rr = 0; rr < 4; ++rr) {
                    const int row = i * 16 + fq * 4 + rr;
                    float v = acc[i][j][rr] + slr[i][rr] * av + cv;
                    v = v / (1.0f + __expf(-v));
                    Hs[row * 512 + ((c8 ^ (row & 7)) * 8) + c7] = __float2bfloat16(v);
                }
        }
    }
    __syncthreads();                    // Hs ready

    // ---- Phase B: 16 iters of k=32, w2-frags direct from global (1-deep)
    f32x4 acc2[2][2] = {};
    float bvv[2];
#pragma unroll
    for (int j = 0; j < 2; ++j) bvv[j] = b2[wave * 32 + j * 16 + fr];
    {
#pragma unroll
        for (int it2 = 0; it2 < 16; ++it2) {
            bf16x8 bcur[2];
#pragma unroll
            for (int j = 0; j < 2; ++j) bcur[j] = bnx2[j];
            if (it2 < 15) {
                const bf16* p = w2base + (size_t)(it2 + 1) * 16384;
#pragma unroll
                for (int j = 0; j < 2; ++j)
                    bnx2[j] = *(const bf16x8*)(p + j * 512);
            }
            bf16x8 af2[2];
#pragma unroll
            for (int i = 0; i < 2; ++i) {
                const int row = i * 16 + fr;
                const int u2  = it2 * 4 + fq;
                af2[i] = *(const bf16x8*)&Hs[row * 512 + ((u2 ^ (row & 7)) * 8)];
            }
#pragma unroll
            for (int i = 0; i < 2; ++i)
#pragma unroll
                for (int j = 0; j < 2; ++j)
                    acc2[i][j] = __builtin_amdgcn_mfma_f32_16x16x32_bf16(
                        af2[i], bcur[j], acc2[i][j], 0, 0, 0);
        }
    }

    // ---- Phase B epilogue: + b2, fp32 out, coalesced
#pragma unroll
    for (int j = 0; j < 2; ++j) {
        const int col = wave * 32 + j * 16 + fr;
        const float bv = bvv[j];
#pragma unroll
        for (int i = 0; i < 2; ++i)
#pragma unroll
            for (int rr = 0; rr < 4; ++rr) {
                const int row = m0 + i * 16 + fq * 4 + rr;
                out[(size_t)row * 512 + col] = acc2[i][j][rr] + bv;
            }
    }
}

// ---------------------------------------------------------------------------
extern "C" void kernel_launch(void* const* d_in, const int* in_sizes, int n_in,
                              void* d_out, int out_size, void* d_ws, size_t ws_size,
                              hipStream_t stream)
{
    const float* x  = (const float*)d_in[0];
    const int*   sL = (const int*)  d_in[1];
    const int*   sC = (const int*)  d_in[2];
    const float* w1 = (const float*)d_in[3];
    const float* b1 = (const float*)d_in[4];
    const float* w2 = (const float*)d_in[5];
    const float* b2 = (const float*)d_in[6];
    float* out = (float*)d_out;

    char* ws = (char*)d_ws;
    bf16*  w1g = (bf16*)ws;                         // 512*1024*2 = 1 MB
    bf16*  w2g = (bf16*)(ws + (1 << 20));           // 512*512*2  = 0.5 MB
    float* A1  = (float*)(ws + (1 << 20) + (1 << 19));
    float* C1  = A1 + DOUT;

    prep<<<896, 256, 0, stream>>>(w1, b1, w2, w1g, w2g, A1, C1);
    mega<<<MM / 32, 1024, 0, stream>>>(x, sL, sC, w1g, w2g, A1, C1, b2, out);
}

// Round 3
// 116.730 us; speedup vs baseline: 1.0611x; 1.0611x over previous
//
#include <hip/hip_runtime.h>
#include <hip/hip_bf16.h>
#include <stdint.h>

// Problem constants
#define LL   4096
#define CCH  64
#define DOUT 512
#define MM   8192            // B*NP patch-rows
#define TT   0.001f          // 1/FS

using bf16 = __hip_bfloat16;
typedef __attribute__((ext_vector_type(8))) short bf16x8;
typedef __attribute__((ext_vector_type(4))) float f32x4;

__device__ __forceinline__ uint2 pack4_bf16(float a, float b, float c, float d) {
    union { bf16 h[4]; uint2 u; } p;
    p.h[0] = __float2bfloat16(a);
    p.h[1] = __float2bfloat16(b);
    p.h[2] = __float2bfloat16(c);
    p.h[3] = __float2bfloat16(d);
    return p.u;
}

// async global->LDS DMA, 16B per lane. LDS dest must be wave-uniform;
// HW writes ldsbase + lane*16. Consumes no VGPRs for the data.
__device__ __forceinline__ void dma16(const bf16* g, bf16* l) {
    __builtin_amdgcn_global_load_lds(
        (const __attribute__((address_space(1))) void*)g,
        (__attribute__((address_space(3))) void*)l, 16, 0, 0);
}

// ---------------------------------------------------------------------------
// prep: repack weights PLAIN (no swizzle) into k-chunked layout so a wave's
// B-fragment load is one contiguous 1 KB block per 16 cols:
//   w1g[ic][col][kk]  (ic=0..31, kk=0..31): = w1[col][l*32+j], k=ic*32+kk,
//                      l=k>>4, j=k&15   (x-part columns only)
//   w2g[ic2][col][kk] (ic2=0..15):        = w2[col][ic2*32+kk]
//   blocks [768,896): A1[o] = T*sum_l Wt[o][l]; C1[o] = b1[o]+T*sum_l l*Wt
//                     Wt[o][l] = sum_{j<16} w1[o][l*32+16+j]      (1 wave/o)
// ---------------------------------------------------------------------------
__global__ __launch_bounds__(256) void prep(
    const float* __restrict__ w1, const float* __restrict__ b1,
    const float* __restrict__ w2,
    bf16* __restrict__ w1g, bf16* __restrict__ w2g,
    float* __restrict__ A1, float* __restrict__ C1)
{
    const int blk = blockIdx.x;
    if (blk < 512) {
        int g   = blk * 256 + threadIdx.x;          // 0..131071, 4 elems each
        int kk0 = (g & 7) * 4;                      // 0,4,..,28
        int col = (g >> 3) & 511;
        int ic  = g >> 12;                          // 0..31
        int l   = ic * 2 + (kk0 >> 4);
        int j0  = kk0 & 15;
        float4 v = *(const float4*)(w1 + (size_t)col * 2048 + l * 32 + j0);
        *(uint2*)(w1g + ((size_t)(ic * 512 + col) * 32 + kk0)) =
            pack4_bf16(v.x, v.y, v.z, v.w);
    } else if (blk < 768) {
        int g   = (blk - 512) * 256 + threadIdx.x;  // 0..65535
        int kk0 = (g & 7) * 4;
        int col = (g >> 3) & 511;
        int ic2 = g >> 12;                          // 0..15
        float4 v = *(const float4*)(w2 + (size_t)col * 512 + ic2 * 32 + kk0);
        *(uint2*)(w2g + ((size_t)(ic2 * 512 + col) * 32 + kk0)) =
            pack4_bf16(v.x, v.y, v.z, v.w);
    } else {
        const int o = (blk - 768) * 4 + (threadIdx.x >> 6);
        const int l = threadIdx.x & 63;
        const float* wr = w1 + (size_t)o * 2048 + l * 32 + 16;
        float s0 = 0.f;
#pragma unroll
        for (int j = 0; j < 16; ++j) s0 += wr[j];
        float s1 = (float)l * s0;
#pragma unroll
        for (int off = 32; off > 0; off >>= 1) {
            s0 += __shfl_down(s0, off);
            s1 += __shfl_down(s1, off);
        }
        if (l == 0) {
            A1[o] = TT * s0;
            C1[o] = b1[o] + TT * s1;
        }
    }
}

// ---------------------------------------------------------------------------
// Megakernel v6: block = 32 patches x 512 outputs, both layers fused.
// v5 post-mortem: duration invariant (43.6us) across 2x occupancy change;
// Little's law fit: in-flight bytes/CU pinned at 32KB, effective latency
// ~2100cy -> duration = traffic * latency / in-flight. Register-staged
// B-loads cap in-flight (compiler folds any deeper ring; v4 proved it).
// v6: B-path via global_load_lds DMA into a WAVE-PRIVATE double-buffered
// LDS ring (2KB/slice). DMA needs no VGPRs (compiler can't re-sink it),
// counted s_waitcnt vmcnt(2) keeps 2 chunks (4KB/wave, 64KB/CU) in flight,
// and there are NO barriers in the k-loops (each wave consumes only what
// it staged). Wave-staggered chunk order (start=2*wave) de-bursts L2.
// Phase-B chunks 0/1 issued before the epilogue; barriers #2/#3 are raw
// s_barrier + lgkmcnt(0) so those DMAs stay in flight across them.
// LDS = 64KB Asm/Hs + 64KB B-ring = 128.1 KB (1 block/CU; grid==CUs).
// ---------------------------------------------------------------------------
__global__ __launch_bounds__(1024, 4) void mega(
    const float* __restrict__ x, const int* __restrict__ sLg,
    const int* __restrict__ sCg, const bf16* __restrict__ w1g,
    const bf16* __restrict__ w2g, const float* __restrict__ A1,
    const float* __restrict__ C1, const float* __restrict__ b2,
    float* __restrict__ out)
{
    __shared__ __align__(16) bf16 Asm[32 * 1024];   // 64 KB; Hs overlays later
    __shared__ __align__(16) bf16 Bb[2][16][1024];  // 64 KB wave-private ring
    __shared__ float slf[32];
    bf16* const Hs = Asm;                           // 32 x 512 after phase A

    const int t    = threadIdx.x;
    const int lane = t & 63;
    const int wave = t >> 6;            // 0..15, owns cols [wave*32, wave*32+32)
    const int fr   = lane & 15;
    const int fq   = lane >> 4;
    const int m0   = blockIdx.x * 32;
    const int b    = m0 >> 8;           // 32 rows lie within one batch

    const int ca0 = wave * 2;           // phase-A chunk stagger start

    // ---- Issue phase-A DMA prologue (chunks ca0, ca0+1) before the gather
#pragma unroll
    for (int k = 0; k < 2; ++k) {
        const int c = (ca0 + k) & 31;
        const bf16* src = w1g + (size_t)c * 16384 + wave * 1024 + lane * 8;
#pragma unroll
        for (int j = 0; j < 2; ++j)
            dma16(src + j * 512, &Bb[k][wave][j * 512]);
    }

    // ---- Prologue: gather x into swizzled A-tile (one shot, 1024 threads)
    {
        const int gr  = t >> 5;         // patch row 0..31
        const int gs  = t & 31;         // 32 threads per patch row
        const int gsl = sLg[m0 + gr];
        const int gsc = sCg[m0 + gr];
        if (gs == 0) slf[gr] = (float)gsl;
        const int c4 = gs & 3;          // which float4 within a 16-ch row
        const int l0 = gs >> 2;         // 0..7 row phase
        const float* gx = x + ((size_t)b * LL + gsl + l0) * CCH
                            + gsc + c4 * 4;
        float4 xv[8];
#pragma unroll
        for (int p = 0; p < 8; ++p)
            xv[p] = *(const float4*)(gx + (size_t)p * 8 * CCH);
#pragma unroll
        for (int p = 0; p < 8; ++p) {
            const int l = p * 8 + l0;
            const int u = l * 2 + (c4 >> 1);            // k-unit = (l*16+j)>>3
            const int idx = gr * 1024 + ((u ^ (gr & 7)) * 8) + (c4 & 1) * 4;
            *(uint2*)(Asm + idx) = pack4_bf16(xv[p].x, xv[p].y, xv[p].z, xv[p].w);
        }
    }
    __syncthreads();      // A-tile ready (drains DMA 0/1 — they arrive under
                          // the ~600cy gather anyway, so the drain is cheap)

    // ---- Phase A: 32 k-chunks, wave-private LDS DMA double-buffer,
    //      counted vmcnt, no barriers.
    f32x4 acc[2][2] = {};
#pragma unroll
    for (int it = 0; it < 32; ++it) {
        if (it == 31) { asm volatile("s_waitcnt vmcnt(0)" ::: "memory"); }
        else          { asm volatile("s_waitcnt vmcnt(2)" ::: "memory"); }
        __builtin_amdgcn_sched_barrier(0);
        const int c = (ca0 + it) & 31;
        const bf16* bs = &Bb[it & 1][wave][0];
        bf16x8 bf[2], af[2];
#pragma unroll
        for (int j = 0; j < 2; ++j)
            bf[j] = *(const bf16x8*)(bs + j * 512 + fr * 32 + fq * 8);
#pragma unroll
        for (int i = 0; i < 2; ++i) {
            const int row = i * 16 + fr;
            const int u   = c * 4 + fq;
            af[i] = *(const bf16x8*)&Asm[row * 1024 + ((u ^ (row & 7)) * 8)];
        }
        // buffer reuse hazard: reads must COMPLETE before re-staging this buf
        asm volatile("s_waitcnt lgkmcnt(0)" ::: "memory");
        __builtin_amdgcn_sched_barrier(0);
        if (it < 30) {
            const int cn = (ca0 + it + 2) & 31;
            const bf16* src = w1g + (size_t)cn * 16384 + wave * 1024 + lane * 8;
#pragma unroll
            for (int j = 0; j < 2; ++j)
                dma16(src + j * 512, &Bb[it & 1][wave][j * 512]);
        }
#pragma unroll
        for (int i = 0; i < 2; ++i)
#pragma unroll
            for (int j = 0; j < 2; ++j)
                acc[i][j] = __builtin_amdgcn_mfma_f32_16x16x32_bf16(
                    af[i], bf[j], acc[i][j], 0, 0, 0);
    }

    // ---- Epilogue scalars; drain them; then issue phase-B DMA chunks 0/1
    //      (they fly under the epilogue + both raw barriers).
    const int cb0 = wave;               // phase-B chunk stagger start
    float avv[2], cvv[2], bvv[2];
#pragma unroll
    for (int j = 0; j < 2; ++j) {
        const int col = wave * 32 + j * 16 + fr;
        avv[j] = A1[col];
        cvv[j] = C1[col];
        bvv[j] = b2[col];
    }
    asm volatile("s_waitcnt vmcnt(0)" ::: "memory");   // scalars done; vm clean
    __builtin_amdgcn_sched_barrier(0);
#pragma unroll
    for (int k = 0; k < 2; ++k) {
        const int c = (cb0 + k) & 15;
        const bf16* src = w2g + (size_t)c * 16384 + wave * 1024 + lane * 8;
#pragma unroll
        for (int j = 0; j < 2; ++j)
            dma16(src + j * 512, &Bb[k][wave][j * 512]);
    }
    asm volatile("s_waitcnt lgkmcnt(0)" ::: "memory");
    __builtin_amdgcn_s_barrier();       // #2: all Asm reads done (raw: keeps
    __builtin_amdgcn_sched_barrier(0);  //     phase-B DMAs in flight)

    // ---- Phase A epilogue: silu(acc + sL*A1 + C1) -> Hs (swizzled)
    {
        float slr[2][4];
#pragma unroll
        for (int i = 0; i < 2; ++i)
#pragma unroll
            for (int rr = 0; rr < 4; ++rr)
                slr[i][rr] = slf[i * 16 + fq * 4 + rr];
#pragma unroll
        for (int j = 0; j < 2; ++j) {
            const int col = wave * 32 + j * 16 + fr;
            const float av = avv[j];
            const float cv = cvv[j];
            const int c8 = col >> 3, c7 = col & 7;
#pragma unroll
            for (int i = 0; i < 2; ++i)
#pragma unroll
                for (int rr = 0; rr < 4; ++rr) {
                    const int row = i * 16 + fq * 4 + rr;
                    float v = acc[i][j][rr] + slr[i][rr] * av + cv;
                    v = v / (1.0f + __expf(-v));
                    Hs[row * 512 + ((c8 ^ (row & 7)) * 8) + c7] = __float2bfloat16(v);
                }
        }
    }
    asm volatile("s_waitcnt lgkmcnt(0)" ::: "memory");
    __builtin_amdgcn_s_barrier();       // #3: Hs ready (raw)
    __builtin_amdgcn_sched_barrier(0);

    // ---- Phase B: 16 k-chunks, same wave-private DMA ring structure
    f32x4 acc2[2][2] = {};
#pragma unroll
    for (int it2 = 0; it2 < 16; ++it2) {
        if (it2 == 15) { asm volatile("s_waitcnt vmcnt(0)" ::: "memory"); }
        else           { asm volatile("s_waitcnt vmcnt(2)" ::: "memory"); }
        __builtin_amdgcn_sched_barrier(0);
        const int c = (cb0 + it2) & 15;
        const bf16* bs = &Bb[it2 & 1][wave][0];
        bf16x8 bf[2], af2[2];
#pragma unroll
        for (int j = 0; j < 2; ++j)
            bf[j] = *(const bf16x8*)(bs + j * 512 + fr * 32 + fq * 8);
#pragma unroll
        for (int i = 0; i < 2; ++i) {
            const int row = i * 16 + fr;
            const int u2  = c * 4 + fq;
            af2[i] = *(const bf16x8*)&Hs[row * 512 + ((u2 ^ (row & 7)) * 8)];
        }
        asm volatile("s_waitcnt lgkmcnt(0)" ::: "memory");
        __builtin_amdgcn_sched_barrier(0);
        if (it2 < 14) {
            const int cn = (cb0 + it2 + 2) & 15;
            const bf16* src = w2g + (size_t)cn * 16384 + wave * 1024 + lane * 8;
#pragma unroll
            for (int j = 0; j < 2; ++j)
                dma16(src + j * 512, &Bb[it2 & 1][wave][j * 512]);
        }
#pragma unroll
        for (int i = 0; i < 2; ++i)
#pragma unroll
            for (int j = 0; j < 2; ++j)
                acc2[i][j] = __builtin_amdgcn_mfma_f32_16x16x32_bf16(
                    af2[i], bf[j], acc2[i][j], 0, 0, 0);
    }

    // ---- Phase B epilogue: + b2, fp32 out, coalesced
#pragma unroll
    for (int j = 0; j < 2; ++j) {
        const int col = wave * 32 + j * 16 + fr;
        const float bv = bvv[j];
#pragma unroll
        for (int i = 0; i < 2; ++i)
#pragma unroll
            for (int rr = 0; rr < 4; ++rr) {
                const int row = m0 + i * 16 + fq * 4 + rr;
                out[(size_t)row * 512 + col] = acc2[i][j][rr] + bv;
            }
    }
}

// ---------------------------------------------------------------------------
extern "C" void kernel_launch(void* const* d_in, const int* in_sizes, int n_in,
                              void* d_out, int out_size, void* d_ws, size_t ws_size,
                              hipStream_t stream)
{
    const float* x  = (const float*)d_in[0];
    const int*   sL = (const int*)  d_in[1];
    const int*   sC = (const int*)  d_in[2];
    const float* w1 = (const float*)d_in[3];
    const float* b1 = (const float*)d_in[4];
    const float* w2 = (const float*)d_in[5];
    const float* b2 = (const float*)d_in[6];
    float* out = (float*)d_out;

    char* ws = (char*)d_ws;
    bf16*  w1g = (bf16*)ws;                         // 512*1024*2 = 1 MB
    bf16*  w2g = (bf16*)(ws + (1 << 20));           // 512*512*2  = 0.5 MB
    float* A1  = (float*)(ws + (1 << 20) + (1 << 19));
    float* C1  = A1 + DOUT;

    prep<<<896, 256, 0, stream>>>(w1, b1, w2, w1g, w2g, A1, C1);
    mega<<<MM / 32, 1024, 0, stream>>>(x, sL, sC, w1g, w2g, A1, C1, b2, out);
}

// Round 4
// 114.306 us; speedup vs baseline: 1.0836x; 1.0212x over previous
//
#include <hip/hip_runtime.h>
#include <hip/hip_bf16.h>
#include <stdint.h>

// Problem constants
#define LL   4096
#define CCH  64
#define DOUT 512
#define MM   8192            // B*NP patch-rows
#define TT   0.001f          // 1/FS

using bf16 = __hip_bfloat16;
typedef __attribute__((ext_vector_type(8))) short bf16x8;
typedef __attribute__((ext_vector_type(4))) float f32x4;

__device__ __forceinline__ uint2 pack4_bf16(float a, float b, float c, float d) {
    union { bf16 h[4]; uint2 u; } p;
    p.h[0] = __float2bfloat16(a);
    p.h[1] = __float2bfloat16(b);
    p.h[2] = __float2bfloat16(c);
    p.h[3] = __float2bfloat16(d);
    return p.u;
}

// async global->LDS DMA, 16B per lane. LDS dest must be wave-uniform;
// HW writes ldsbase + lane*16. Consumes no VGPRs for the data.
__device__ __forceinline__ void dma16(const bf16* g, bf16* l) {
    __builtin_amdgcn_global_load_lds(
        (const __attribute__((address_space(1))) void*)g,
        (__attribute__((address_space(3))) void*)l, 16, 0, 0);
}

// ---------------------------------------------------------------------------
// prep: repack weights PLAIN (no swizzle) into k-chunked layout so a wave's
// B-fragment load is one contiguous 1 KB block per 16 cols:
//   w1g[ic][col][kk]  (ic=0..31, kk=0..31): = w1[col][l*32+j], k=ic*32+kk,
//                      l=k>>4, j=k&15   (x-part columns only)
//   w2g[ic2][col][kk] (ic2=0..15):        = w2[col][ic2*32+kk]
//   blocks [768,896): A1[o] = T*sum_l Wt[o][l]; C1[o] = b1[o]+T*sum_l l*Wt
//                     Wt[o][l] = sum_{j<16} w1[o][l*32+16+j]      (1 wave/o)
// ---------------------------------------------------------------------------
__global__ __launch_bounds__(256) void prep(
    const float* __restrict__ w1, const float* __restrict__ b1,
    const float* __restrict__ w2,
    bf16* __restrict__ w1g, bf16* __restrict__ w2g,
    float* __restrict__ A1, float* __restrict__ C1)
{
    const int blk = blockIdx.x;
    if (blk < 512) {
        int g   = blk * 256 + threadIdx.x;          // 0..131071, 4 elems each
        int kk0 = (g & 7) * 4;                      // 0,4,..,28
        int col = (g >> 3) & 511;
        int ic  = g >> 12;                          // 0..31
        int l   = ic * 2 + (kk0 >> 4);
        int j0  = kk0 & 15;
        float4 v = *(const float4*)(w1 + (size_t)col * 2048 + l * 32 + j0);
        *(uint2*)(w1g + ((size_t)(ic * 512 + col) * 32 + kk0)) =
            pack4_bf16(v.x, v.y, v.z, v.w);
    } else if (blk < 768) {
        int g   = (blk - 512) * 256 + threadIdx.x;  // 0..65535
        int kk0 = (g & 7) * 4;
        int col = (g >> 3) & 511;
        int ic2 = g >> 12;                          // 0..15
        float4 v = *(const float4*)(w2 + (size_t)col * 512 + ic2 * 32 + kk0);
        *(uint2*)(w2g + ((size_t)(ic2 * 512 + col) * 32 + kk0)) =
            pack4_bf16(v.x, v.y, v.z, v.w);
    } else {
        const int o = (blk - 768) * 4 + (threadIdx.x >> 6);
        const int l = threadIdx.x & 63;
        const float* wr = w1 + (size_t)o * 2048 + l * 32 + 16;
        float s0 = 0.f;
#pragma unroll
        for (int j = 0; j < 16; ++j) s0 += wr[j];
        float s1 = (float)l * s0;
#pragma unroll
        for (int off = 32; off > 0; off >>= 1) {
            s0 += __shfl_down(s0, off);
            s1 += __shfl_down(s1, off);
        }
        if (l == 0) {
            A1[o] = TT * s0;
            C1[o] = b1[o] + TT * s1;
        }
    }
}

// ---------------------------------------------------------------------------
// Megakernel v7: block = 32 patches x 512 outputs, both layers fused.
// v6 post-mortem (mega ~37us): (a) 2-slot ring + vmcnt(2) left only ONE
// chunk in flight during compute (32KB/CU, same as v5 -- depth-N needs N+1
// buffers); (b) ca0=wave*2 identical across blocks -> all 32 CUs of an XCD
// request the SAME 2KB chunk simultaneously -> L2 bank hotspot (aggregate
// weight ingest measured 10.2 TB/s vs 34.5 L2 ceiling; implied ~1.5us
// chunk latency).
// v7: (1) 3-slot ring, counted vmcnt(4) -> 2 chunks (4KB/wave, 64KB/CU) in
// flight during compute; (2) per-block chunk-sweep offset (blk>>3)&31 so
// the 32 same-XCD blocks sweep 32 DISTINCT chunks at any instant.
// LDS = 64KB Asm/Hs + 96KB ring = exactly 160KB; slf dropped (epilogue
// reloads start_L from global, issued post-loop, flies under barriers).
// No barriers inside the k-loops (wave-private ring).
// ---------------------------------------------------------------------------
__global__ __launch_bounds__(1024, 4) void mega(
    const float* __restrict__ x, const int* __restrict__ sLg,
    const int* __restrict__ sCg, const bf16* __restrict__ w1g,
    const bf16* __restrict__ w2g, const float* __restrict__ A1,
    const float* __restrict__ C1, const float* __restrict__ b2,
    float* __restrict__ out)
{
    __shared__ __align__(16) bf16 Asm[32 * 1024];   // 64 KB; Hs overlays later
    __shared__ __align__(16) bf16 Bb[3][16][1024];  // 96 KB wave-private ring
    bf16* const Hs = Asm;                           // 32 x 512 after phase A

    const int t    = threadIdx.x;
    const int lane = t & 63;
    const int wave = t >> 6;            // 0..15, owns cols [wave*32, wave*32+32)
    const int fr   = lane & 15;
    const int fq   = lane >> 4;
    const int m0   = blockIdx.x * 32;
    const int b    = m0 >> 8;           // 32 rows lie within one batch

    // de-correlate chunk sweeps: same-XCD blocks (blk%8==XCD) get distinct
    // offsets 0..31 via blk>>3.
    const int coff = (blockIdx.x >> 3);
    const int ca0  = (wave * 2 + coff) & 31;        // phase-A stagger start
    const int cb0  = (wave + coff) & 15;            // phase-B stagger start

    // ---- Issue phase-A DMA prologue (chunks ca0..ca0+2) before the gather
#pragma unroll
    for (int k = 0; k < 3; ++k) {
        const int c = (ca0 + k) & 31;
        const bf16* src = w1g + (size_t)c * 16384 + wave * 1024 + lane * 8;
#pragma unroll
        for (int j = 0; j < 2; ++j)
            dma16(src + j * 512, &Bb[k][wave][j * 512]);
    }

    // ---- Prologue: gather x into swizzled A-tile (one shot, 1024 threads)
    {
        const int gr  = t >> 5;         // patch row 0..31
        const int gs  = t & 31;         // 32 threads per patch row
        const int gsl = sLg[m0 + gr];
        const int gsc = sCg[m0 + gr];
        const int c4 = gs & 3;          // which float4 within a 16-ch row
        const int l0 = gs >> 2;         // 0..7 row phase
        const float* gx = x + ((size_t)b * LL + gsl + l0) * CCH
                            + gsc + c4 * 4;
        float4 xv[8];
#pragma unroll
        for (int p = 0; p < 8; ++p)
            xv[p] = *(const float4*)(gx + (size_t)p * 8 * CCH);
#pragma unroll
        for (int p = 0; p < 8; ++p) {
            const int l = p * 8 + l0;
            const int u = l * 2 + (c4 >> 1);            // k-unit = (l*16+j)>>3
            const int idx = gr * 1024 + ((u ^ (gr & 7)) * 8) + (c4 & 1) * 4;
            *(uint2*)(Asm + idx) = pack4_bf16(xv[p].x, xv[p].y, xv[p].z, xv[p].w);
        }
    }
    __syncthreads();                    // A-tile ready

    // ---- Phase A: 32 k-chunks, wave-private 3-slot LDS DMA ring,
    //      counted vmcnt (2 chunks in flight during compute), no barriers.
    f32x4 acc[2][2] = {};
#pragma unroll
    for (int it = 0; it < 32; ++it) {
        if (it <= 29)      { asm volatile("s_waitcnt vmcnt(4)" ::: "memory"); }
        else if (it == 30) { asm volatile("s_waitcnt vmcnt(2)" ::: "memory"); }
        else               { asm volatile("s_waitcnt vmcnt(0)" ::: "memory"); }
        __builtin_amdgcn_sched_barrier(0);
        const int c = (ca0 + it) & 31;
        const bf16* bs = &Bb[it % 3][wave][0];
        bf16x8 bf[2], af[2];
#pragma unroll
        for (int j = 0; j < 2; ++j)
            bf[j] = *(const bf16x8*)(bs + j * 512 + fr * 32 + fq * 8);
#pragma unroll
        for (int i = 0; i < 2; ++i) {
            const int row = i * 16 + fr;
            const int u   = c * 4 + fq;
            af[i] = *(const bf16x8*)&Asm[row * 1024 + ((u ^ (row & 7)) * 8)];
        }
        // buffer reuse hazard: reads must COMPLETE before re-staging this buf
        asm volatile("s_waitcnt lgkmcnt(0)" ::: "memory");
        __builtin_amdgcn_sched_barrier(0);
        if (it < 29) {
            const int cn = (ca0 + it + 3) & 31;
            const bf16* src = w1g + (size_t)cn * 16384 + wave * 1024 + lane * 8;
#pragma unroll
            for (int j = 0; j < 2; ++j)
                dma16(src + j * 512, &Bb[it % 3][wave][j * 512]);
        }
#pragma unroll
        for (int i = 0; i < 2; ++i)
#pragma unroll
            for (int j = 0; j < 2; ++j)
                acc[i][j] = __builtin_amdgcn_mfma_f32_16x16x32_bf16(
                    af[i], bf[j], acc[i][j], 0, 0, 0);
    }

    // ---- Epilogue scalars (start_L rows + A1/C1/b2), then issue phase-B
    //      DMA chunks 0..2 (they fly under the epilogue + both raw barriers).
    float slr[2][4];
#pragma unroll
    for (int i = 0; i < 2; ++i)
#pragma unroll
        for (int rr = 0; rr < 4; ++rr)
            slr[i][rr] = (float)sLg[m0 + i * 16 + fq * 4 + rr];
    float avv[2], cvv[2], bvv[2];
#pragma unroll
    for (int j = 0; j < 2; ++j) {
        const int col = wave * 32 + j * 16 + fr;
        avv[j] = A1[col];
        cvv[j] = C1[col];
        bvv[j] = b2[col];
    }
#pragma unroll
    for (int k = 0; k < 3; ++k) {
        const int c = (cb0 + k) & 15;
        const bf16* src = w2g + (size_t)c * 16384 + wave * 1024 + lane * 8;
#pragma unroll
        for (int j = 0; j < 2; ++j)
            dma16(src + j * 512, &Bb[k][wave][j * 512]);
    }
    asm volatile("s_waitcnt lgkmcnt(0)" ::: "memory");
    __builtin_amdgcn_s_barrier();       // #2: all Asm reads done (raw: keeps
    __builtin_amdgcn_sched_barrier(0);  //     phase-B DMAs in flight)

    // ---- Phase A epilogue: silu(acc + sL*A1 + C1) -> Hs (swizzled)
    {
#pragma unroll
        for (int j = 0; j < 2; ++j) {
            const int col = wave * 32 + j * 16 + fr;
            const float av = avv[j];
            const float cv = cvv[j];
            const int c8 = col >> 3, c7 = col & 7;
#pragma unroll
            for (int i = 0; i < 2; ++i)
#pragma unroll
                for (int rr = 0; rr < 4; ++rr) {
                    const int row = i * 16 + fq * 4 + rr;
                    float v = acc[i][j][rr] + slr[i][rr] * av + cv;
                    v = v / (1.0f + __expf(-v));
                    Hs[row * 512 + ((c8 ^ (row & 7)) * 8) + c7] = __float2bfloat16(v);
                }
        }
    }
    asm volatile("s_waitcnt lgkmcnt(0)" ::: "memory");
    __builtin_amdgcn_s_barrier();       // #3: Hs ready (raw)
    __builtin_amdgcn_sched_barrier(0);

    // ---- Phase B: 16 k-chunks, same wave-private 3-slot DMA ring
    f32x4 acc2[2][2] = {};
#pragma unroll
    for (int it2 = 0; it2 < 16; ++it2) {
        if (it2 <= 13)      { asm volatile("s_waitcnt vmcnt(4)" ::: "memory"); }
        else if (it2 == 14) { asm volatile("s_waitcnt vmcnt(2)" ::: "memory"); }
        else                { asm volatile("s_waitcnt vmcnt(0)" ::: "memory"); }
        __builtin_amdgcn_sched_barrier(0);
        const int c = (cb0 + it2) & 15;
        const bf16* bs = &Bb[it2 % 3][wave][0];
        bf16x8 bf[2], af2[2];
#pragma unroll
        for (int j = 0; j < 2; ++j)
            bf[j] = *(const bf16x8*)(bs + j * 512 + fr * 32 + fq * 8);
#pragma unroll
        for (int i = 0; i < 2; ++i) {
            const int row = i * 16 + fr;
            const int u2  = c * 4 + fq;
            af2[i] = *(const bf16x8*)&Hs[row * 512 + ((u2 ^ (row & 7)) * 8)];
        }
        asm volatile("s_waitcnt lgkmcnt(0)" ::: "memory");
        __builtin_amdgcn_sched_barrier(0);
        if (it2 < 13) {
            const int cn = (cb0 + it2 + 3) & 15;
            const bf16* src = w2g + (size_t)cn * 16384 + wave * 1024 + lane * 8;
#pragma unroll
            for (int j = 0; j < 2; ++j)
                dma16(src + j * 512, &Bb[it2 % 3][wave][j * 512]);
        }
#pragma unroll
        for (int i = 0; i < 2; ++i)
#pragma unroll
            for (int j = 0; j < 2; ++j)
                acc2[i][j] = __builtin_amdgcn_mfma_f32_16x16x32_bf16(
                    af2[i], bf[j], acc2[i][j], 0, 0, 0);
    }

    // ---- Phase B epilogue: + b2, fp32 out, coalesced
#pragma unroll
    for (int j = 0; j < 2; ++j) {
        const int col = wave * 32 + j * 16 + fr;
        const float bv = bvv[j];
#pragma unroll
        for (int i = 0; i < 2; ++i)
#pragma unroll
            for (int rr = 0; rr < 4; ++rr) {
                const int row = m0 + i * 16 + fq * 4 + rr;
                out[(size_t)row * 512 + col] = acc2[i][j][rr] + bv;
            }
    }
}

// ---------------------------------------------------------------------------
extern "C" void kernel_launch(void* const* d_in, const int* in_sizes, int n_in,
                              void* d_out, int out_size, void* d_ws, size_t ws_size,
                              hipStream_t stream)
{
    const float* x  = (const float*)d_in[0];
    const int*   sL = (const int*)  d_in[1];
    const int*   sC = (const int*)  d_in[2];
    const float* w1 = (const float*)d_in[3];
    const float* b1 = (const float*)d_in[4];
    const float* w2 = (const float*)d_in[5];
    const float* b2 = (const float*)d_in[6];
    float* out = (float*)d_out;

    char* ws = (char*)d_ws;
    bf16*  w1g = (bf16*)ws;                         // 512*1024*2 = 1 MB
    bf16*  w2g = (bf16*)(ws + (1 << 20));           // 512*512*2  = 0.5 MB
    float* A1  = (float*)(ws + (1 << 20) + (1 << 19));
    float* C1  = A1 + DOUT;

    prep<<<896, 256, 0, stream>>>(w1, b1, w2, w1g, w2g, A1, C1);
    mega<<<MM / 32, 1024, 0, stream>>>(x, sL, sC, w1g, w2g, A1, C1, b2, out);
}